// Round 1
// baseline (548.842 us; speedup 1.0000x reference)
//
#include <hip/hip_runtime.h>

// MambaSP fully-fused: 4 layers x (preprocess + chunked selective scan) in ONE kernel.
// Grid = (NC=32 chunks, B=32) = 1024 blocks x 128 thr = exactly 4 blocks/CU on 256 CUs
// (LDS 36.9KB/block -> 4/CU; all blocks co-resident => spin-waits are deadlock-free;
//  additionally every dependency points to a strictly lower linear block id).
// Per layer, per block:
//   A: preprocess (conv+silu+softplus) from LDS input -> s_ud (LDS, never global)
//   B: local scan -> aggregate (P,S) -> global + release flag
//   C: deterministic full lookback over predecessor chunks' (P,S) -> h_init
//   D: re-scan with h_init, LDS n-reduction, fused epilogue -> next-layer input in LDS
//   E: publish 3-float conv halo for right neighbor (flagged), swap input
// Inter-layer traffic: 3 floats/block. K2 kernel + ud global round-trip eliminated.

constexpr int   Bsz = 32;
constexpr int   Lsz = 4096;
constexpr int   NC  = 32;          // chunks per sequence
constexpr int   CL  = 128;         // chunk length
constexpr int   NL  = 4;           // layers
constexpr float SRinv = 1.0f / 4096.0f;

__device__ __forceinline__ float sigmoidf_(float v) {
    return 1.0f / (1.0f + __expf(-v));
}

__global__ __launch_bounds__(128) void k_mamba_fused(
    const float* __restrict__ xin,    // [B,L]
    const float* __restrict__ W_in,   // [NL,1,4]
    const float* __restrict__ conv_w, // [NL,2,4]
    const float* __restrict__ conv_b, // [NL,2]
    const float* __restrict__ W_x,    // [NL,2,129]
    const float* __restrict__ W_dt,   // [NL,1,2]
    const float* __restrict__ b_dt,   // [NL,2]
    const float* __restrict__ A_log,  // [NL,2,64]
    const float* __restrict__ D_skip, // [NL,2]
    const float* __restrict__ W_out,  // [NL,2,1]
    int*   __restrict__ flags,        // [2][NL][B][NC]  (agg flags, halo flags)
    float* __restrict__ Pc,           // [NL][B][NC][128]
    float* __restrict__ Sc,           // [NL][B][NC][128]
    float* __restrict__ halo,         // [NL][B][NC][4]
    float* __restrict__ out)          // [B,L]
{
    const int c = blockIdx.x, b = blockIdx.y, tid = threadIdx.x;
    constexpr int T = 64;             // reduction tile
    __shared__ float  xs[CL + 3];     // layer input with 3-left-halo
    __shared__ float4 s_ud[CL];       // {u0,u1,d0,d1}
    __shared__ float  ps[128 * 65];   // reduction scratch, stride 65 (bank-safe)
    __shared__ float  ys[2 * T];
    __shared__ float  yn[CL];         // this layer's output chunk

    const int base = b * Lsz + c * CL;
    const int e = tid >> 6, n = tid & 63;

    // layer-0 input (+zero-padded halo)
    for (int i = tid; i < CL + 3; i += 128) {
        int l = c * CL + i - 3;
        xs[i] = (l >= 0) ? xin[b * Lsz + l] : 0.0f;
    }

    for (int layer = 0; layer < NL; ++layer) {
        const float* Wi = W_in   + layer * 4;
        const float* cw = conv_w + layer * 8;
        const float* cb = conv_b + layer * 2;
        const float* Wx = W_x    + layer * 258;
        const float* Wd = W_dt   + layer * 2;
        const float* bd = b_dt   + layer * 2;
        const float* Al = A_log  + layer * 128;
        const float* Ds = D_skip + layer * 2;
        const float* Wo = W_out  + layer * 2;
        float* Pl = Pc + (size_t)(layer * Bsz + b) * NC * 128;
        float* Sl = Sc + (size_t)(layer * Bsz + b) * NC * 128;
        float* Hl = halo + (size_t)(layer * Bsz + b) * NC * 4;
        int* fA = flags + (layer * Bsz + b) * NC;
        int* fH = flags + NL * Bsz * NC + (layer * Bsz + b) * NC;

        __syncthreads();   // xs ready

        // ---- A: preprocess position t = tid ----
        {
            const int t = tid;
            float x0 = xs[t], x1 = xs[t + 1], x2 = xs[t + 2], x3 = xs[t + 3];
            float u[2];
            #pragma unroll
            for (int ee = 0; ee < 2; ee++) {
                float v = Wi[ee] * (x0 * cw[ee * 4 + 0] + x1 * cw[ee * 4 + 1] +
                                    x2 * cw[ee * 4 + 2] + x3 * cw[ee * 4 + 3]) +
                          cb[ee];
                u[ee] = v * sigmoidf_(v);   // silu
            }
            float dt = u[0] * Wx[0] + u[1] * Wx[129];
            float dl[2];
            #pragma unroll
            for (int ee = 0; ee < 2; ee++) {
                float a = dt * Wd[ee] + bd[ee];
                float sp = (a > 20.0f) ? a : log1pf(__expf(a));
                dl[ee] = sp * SRinv;
            }
            s_ud[t] = make_float4(u[0], u[1], dl[0], dl[1]);
        }
        __syncthreads();

        // ---- B: local chunk scan -> (P,S), publish ----
        const float Aen = -__expf(Al[e * 64 + n]);
        const float wb0 = Wx[1 + n], wb1 = Wx[129 + 1 + n];
        float P = 1.0f, S = 0.0f;
        #pragma unroll 8
        for (int l = 0; l < CL; l++) {
            float4 v = s_ud[l];
            float ue = e ? v.y : v.x;
            float d  = e ? v.w : v.z;
            float Bn = v.x * wb0 + v.y * wb1;
            float dA = __expf(d * Aen);
            S = dA * S + (d * ue) * Bn;
            P *= dA;
        }
        Pl[c * 128 + tid] = P;
        Sl[c * 128 + tid] = S;
        __threadfence();                 // each thread drains its own stores device-wide
        __syncthreads();
        if (tid == 0)
            __hip_atomic_store(&fA[c], 1, __ATOMIC_RELEASE, __HIP_MEMORY_SCOPE_AGENT);

        // ---- C: deterministic full lookback -> h_in ----
        float hin = 0.0f;
        if (c > 0) {
            for (int j = tid; j < c; j += 128)
                while (__hip_atomic_load(&fA[j], __ATOMIC_RELAXED, __HIP_MEMORY_SCOPE_AGENT) == 0)
                    __builtin_amdgcn_s_sleep(2);
            __syncthreads();
            __threadfence();             // acquire: invalidate caches before data reads
            float runS = 0.0f, runP = 1.0f;
            #pragma unroll 4
            for (int j = c - 1; j >= 0; --j) {
                float Sj = Sl[j * 128 + tid];
                float Pj = Pl[j * 128 + tid];
                runS = __fmaf_rn(runP, Sj, runS);
                runP *= Pj;
            }
            hin = runS;
        }

        // ---- D: re-scan with init state + n-reduction + fused epilogue ----
        const float wc0 = Wx[65 + n], wc1 = Wx[129 + 65 + n];
        const float wz0 = Wi[2], wz1 = Wi[3];
        const float D0 = Ds[0], D1 = Ds[1];
        const float wo0 = Wo[0], wo1 = Wo[1];
        float h = hin;
        for (int tile = 0; tile < CL / T; ++tile) {
            #pragma unroll 8
            for (int t = 0; t < T; t++) {
                float4 v = s_ud[tile * T + t];
                float ue = e ? v.y : v.x;
                float d  = e ? v.w : v.z;
                float Bn = v.x * wb0 + v.y * wb1;
                float Cn = v.x * wc0 + v.y * wc1;
                float dA = __expf(d * Aen);
                h = dA * h + (d * ue) * Bn;
                ps[(t * 2 + e) * 65 + n] = h * Cn;
            }
            __syncthreads();
            {   // reduce row r over n (64 values), add u*D
                const int r = tid, t = r >> 1, re = r & 1;
                const float* row = &ps[r * 65];
                float a0 = 0, a1 = 0, a2 = 0, a3 = 0;
                #pragma unroll
                for (int j = 0; j < 64; j += 4) {
                    a0 += row[j]; a1 += row[j + 1]; a2 += row[j + 2]; a3 += row[j + 3];
                }
                float4 v = s_ud[tile * T + t];
                float ue = re ? v.y : v.x;
                ys[r] = (a0 + a1) + (a2 + a3) + ue * (re ? D1 : D0);
            }
            __syncthreads();
            if (tid < T) {
                int l = tile * T + tid;
                float y0 = ys[tid * 2], y1 = ys[tid * 2 + 1];
                float xv = xs[3 + l];                       // note: xs has halo offset 3
                float z0 = xv * wz0, z1 = xv * wz1;
                float yv = y0 * (z0 * sigmoidf_(z0)) * wo0 +
                           y1 * (z1 * sigmoidf_(z1)) * wo1 + xv;
                if (layer == NL - 1) out[base + l] = yv;
                else                 yn[l] = yv;
            }
            __syncthreads();
        }

        // ---- E: halo publish + input swap for next layer ----
        if (layer < NL - 1) {
            if (tid == 0 && c < NC - 1) {
                Hl[c * 4 + 0] = yn[125];
                Hl[c * 4 + 1] = yn[126];
                Hl[c * 4 + 2] = yn[127];
                __threadfence();
                __hip_atomic_store(&fH[c], 1, __ATOMIC_RELEASE, __HIP_MEMORY_SCOPE_AGENT);
            }
            xs[3 + tid] = yn[tid];
            if (tid < 3) {
                float hv = 0.0f;
                if (c > 0) {
                    while (__hip_atomic_load(&fH[c - 1], __ATOMIC_RELAXED, __HIP_MEMORY_SCOPE_AGENT) == 0)
                        __builtin_amdgcn_s_sleep(2);
                    __threadfence();
                    hv = Hl[(c - 1) * 4 + tid];
                }
                xs[tid] = hv;
            }
            // top-of-loop __syncthreads orders xs for next preprocess
        }
    }
}

extern "C" void kernel_launch(void* const* d_in, const int* in_sizes, int n_in,
                              void* d_out, int out_size, void* d_ws, size_t ws_size,
                              hipStream_t stream) {
    const float* x      = (const float*)d_in[0];
    const float* W_in   = (const float*)d_in[1];   // [4,1,4]
    const float* conv_w = (const float*)d_in[2];   // [4,2,4]
    const float* conv_b = (const float*)d_in[3];   // [4,2]
    const float* W_x    = (const float*)d_in[4];   // [4,2,129]
    const float* W_dt   = (const float*)d_in[5];   // [4,1,2]
    const float* b_dt   = (const float*)d_in[6];   // [4,2]
    const float* A_log  = (const float*)d_in[7];   // [4,2,64]
    const float* D_skip = (const float*)d_in[8];   // [4,2]
    const float* W_out  = (const float*)d_in[9];   // [4,2,1]
    float* out = (float*)d_out;

    // workspace: flags (8192 ints) | Pc | Sc | halo   (~4.3 MB total)
    int*   flags = (int*)d_ws;
    float* Pc    = (float*)d_ws + 8192;
    float* Sc    = Pc + (size_t)NL * Bsz * NC * 128;
    float* halo  = Sc + (size_t)NL * Bsz * NC * 128;

    hipMemsetAsync(flags, 0, 8192 * sizeof(int), stream);
    k_mamba_fused<<<dim3(NC, Bsz), 128, 0, stream>>>(
        x, W_in, conv_w, conv_b, W_x, W_dt, b_dt, A_log, D_skip, W_out,
        flags, Pc, Sc, halo, out);
}

// Round 2
// 448.148 us; speedup vs baseline: 1.2247x; 1.2247x over previous
//
#include <hip/hip_runtime.h>

// MambaSP fully-fused, fence-free revision.
// Round-1 post-mortem: __threadfence() at agent scope on gfx950 = buffer_wbl2/buffer_inv
// (whole-L2 writeback/invalidate). ~14K of those per launch caused a cache-maintenance
// storm: 494us kernel with 11% VALUBusy. This version has ZERO threadfences:
//   - publishers: normal cached stores -> __syncthreads -> ONE release atomicOr (tid 0).
//     The release flushes the publisher's dirty lines to the coherence point (LLC).
//   - consumers: poll ONE mask word per (layer,b) with a relaxed atomic RMW (always
//     executes at LLC, stale-proof), then read data with relaxed agent atomic loads
//     (sc0+sc1 -> LLC-direct). No acquire-invalidate needed anywhere.
// Grid = (NC=32, B=32) = 1024 blocks x 128thr, LDS 37.4KB -> exactly 4 blocks/CU on
// 256 CUs: all blocks co-resident, and every wait targets a strictly lower chunk id.

constexpr int   Bsz = 32;
constexpr int   Lsz = 4096;
constexpr int   NC  = 32;          // chunks per sequence
constexpr int   CL  = 128;         // chunk length
constexpr int   NL  = 4;           // layers
constexpr float SRinv = 1.0f / 4096.0f;

__device__ __forceinline__ float sigmoidf_(float v) {
    return 1.0f / (1.0f + __expf(-v));
}

__device__ __forceinline__ float ucload(const float* p) {   // uncached (LLC) load
    return __hip_atomic_load(p, __ATOMIC_RELAXED, __HIP_MEMORY_SCOPE_AGENT);
}

__global__ __launch_bounds__(128) void k_mamba_fused(
    const float* __restrict__ xin,    // [B,L]
    const float* __restrict__ W_in,   // [NL,1,4]
    const float* __restrict__ conv_w, // [NL,2,4]
    const float* __restrict__ conv_b, // [NL,2]
    const float* __restrict__ W_x,    // [NL,2,129]
    const float* __restrict__ W_dt,   // [NL,1,2]
    const float* __restrict__ b_dt,   // [NL,2]
    const float* __restrict__ A_log,  // [NL,2,64]
    const float* __restrict__ D_skip, // [NL,2]
    const float* __restrict__ W_out,  // [NL,2,1]
    unsigned* __restrict__ aggMask,   // [NL][B]  bit c = chunk c aggregates published
    unsigned* __restrict__ haloMask,  // [NL][B]  bit c = chunk c halo published
    float* __restrict__ Pc,           // [NL][B][NC][128]
    float* __restrict__ Sc,           // [NL][B][NC][128]
    float* __restrict__ halo,         // [NL][B][NC][4]
    float* __restrict__ out)          // [B,L]
{
    const int c = blockIdx.x, b = blockIdx.y, tid = threadIdx.x;
    constexpr int T = 64;             // reduction tile
    __shared__ float  xs[CL + 3];     // layer input with 3-left-halo
    __shared__ float4 s_ud[CL];       // {u0,u1,d0,d1}
    __shared__ float  ps[128 * 65];   // reduction scratch, stride 65 (bank-safe)
    __shared__ float  ys[2 * T];
    __shared__ float  yn[CL];         // this layer's output chunk

    const int base = b * Lsz + c * CL;
    const int e = tid >> 6, n = tid & 63;

    // layer-0 input (+zero-padded halo)
    for (int i = tid; i < CL + 3; i += 128) {
        int l = c * CL + i - 3;
        xs[i] = (l >= 0) ? xin[b * Lsz + l] : 0.0f;
    }

    for (int layer = 0; layer < NL; ++layer) {
        const float* Wi = W_in   + layer * 4;
        const float* cw = conv_w + layer * 8;
        const float* cb = conv_b + layer * 2;
        const float* Wx = W_x    + layer * 258;
        const float* Wd = W_dt   + layer * 2;
        const float* bd = b_dt   + layer * 2;
        const float* Al = A_log  + layer * 128;
        const float* Ds = D_skip + layer * 2;
        const float* Wo = W_out  + layer * 2;
        float* Pl = Pc   + (size_t)(layer * Bsz + b) * NC * 128;
        float* Sl = Sc   + (size_t)(layer * Bsz + b) * NC * 128;
        float* Hl = halo + (size_t)(layer * Bsz + b) * NC * 4;
        unsigned* aM = aggMask  + layer * Bsz + b;
        unsigned* hM = haloMask + layer * Bsz + b;

        __syncthreads();   // xs ready

        // ---- A: preprocess position t = tid ----
        {
            const int t = tid;
            float x0 = xs[t], x1 = xs[t + 1], x2 = xs[t + 2], x3 = xs[t + 3];
            float u[2];
            #pragma unroll
            for (int ee = 0; ee < 2; ee++) {
                float v = Wi[ee] * (x0 * cw[ee * 4 + 0] + x1 * cw[ee * 4 + 1] +
                                    x2 * cw[ee * 4 + 2] + x3 * cw[ee * 4 + 3]) +
                          cb[ee];
                u[ee] = v * sigmoidf_(v);   // silu
            }
            float dt = u[0] * Wx[0] + u[1] * Wx[129];
            float dl[2];
            #pragma unroll
            for (int ee = 0; ee < 2; ee++) {
                float a = dt * Wd[ee] + bd[ee];
                float sp = (a > 20.0f) ? a : log1pf(__expf(a));
                dl[ee] = sp * SRinv;
            }
            s_ud[t] = make_float4(u[0], u[1], dl[0], dl[1]);
        }
        __syncthreads();

        // ---- B: local chunk scan -> (P,S), publish (normal stores + 1 release flag) ----
        const float Aen = -__expf(Al[e * 64 + n]);
        const float wb0 = Wx[1 + n], wb1 = Wx[129 + 1 + n];
        float P = 1.0f, S = 0.0f;
        #pragma unroll 8
        for (int l = 0; l < CL; l++) {
            float4 v = s_ud[l];
            float ue = e ? v.y : v.x;
            float d  = e ? v.w : v.z;
            float Bn = v.x * wb0 + v.y * wb1;
            float dA = __expf(d * Aen);
            S = dA * S + (d * ue) * Bn;
            P *= dA;
        }
        if (c < NC - 1) {                 // chunk 31's aggregates are never consumed
            Pl[c * 128 + tid] = P;
            Sl[c * 128 + tid] = S;
        }
        __syncthreads();                  // all threads' stores drained (barrier semantics)
        if (tid == 0 && c < NC - 1)
            __hip_atomic_fetch_or(aM, 1u << c, __ATOMIC_RELEASE, __HIP_MEMORY_SCOPE_AGENT);

        // ---- C: deterministic full lookback over local aggregates -> h_in ----
        float hin = 0.0f;
        if (c > 0) {
            const unsigned need = (1u << c) - 1u;
            if (tid == 0) {
                // RMW-based poll: executes at the coherence point, cannot read stale.
                while ((__hip_atomic_fetch_or(aM, 0u, __ATOMIC_RELAXED,
                                              __HIP_MEMORY_SCOPE_AGENT) & need) != need)
                    __builtin_amdgcn_s_sleep(2);
            }
            __syncthreads();
            float runS = 0.0f, runP = 1.0f;
            #pragma unroll 8
            for (int j = c - 1; j >= 0; --j) {
                float Sj = ucload(&Sl[j * 128 + tid]);
                float Pj = ucload(&Pl[j * 128 + tid]);
                runS = __fmaf_rn(runP, Sj, runS);
                runP *= Pj;
            }
            hin = runS;
        }

        // ---- D: re-scan with init state + n-reduction + fused epilogue ----
        const float wc0 = Wx[65 + n], wc1 = Wx[129 + 65 + n];
        const float wz0 = Wi[2], wz1 = Wi[3];
        const float D0 = Ds[0], D1 = Ds[1];
        const float wo0 = Wo[0], wo1 = Wo[1];
        float h = hin;
        for (int tile = 0; tile < CL / T; ++tile) {
            #pragma unroll 8
            for (int t = 0; t < T; t++) {
                float4 v = s_ud[tile * T + t];
                float ue = e ? v.y : v.x;
                float d  = e ? v.w : v.z;
                float Bn = v.x * wb0 + v.y * wb1;
                float Cn = v.x * wc0 + v.y * wc1;
                float dA = __expf(d * Aen);
                h = dA * h + (d * ue) * Bn;
                ps[(t * 2 + e) * 65 + n] = h * Cn;
            }
            __syncthreads();
            {   // reduce row r over n (64 values), add u*D
                const int r = tid, t = r >> 1, re = r & 1;
                const float* row = &ps[r * 65];
                float a0 = 0, a1 = 0, a2 = 0, a3 = 0;
                #pragma unroll
                for (int j = 0; j < 64; j += 4) {
                    a0 += row[j]; a1 += row[j + 1]; a2 += row[j + 2]; a3 += row[j + 3];
                }
                float4 v = s_ud[tile * T + t];
                float ue = re ? v.y : v.x;
                ys[r] = (a0 + a1) + (a2 + a3) + ue * (re ? D1 : D0);
            }
            __syncthreads();
            if (tid < T) {
                int l = tile * T + tid;
                float y0 = ys[tid * 2], y1 = ys[tid * 2 + 1];
                float xv = xs[3 + l];
                float z0 = xv * wz0, z1 = xv * wz1;
                float yv = y0 * (z0 * sigmoidf_(z0)) * wo0 +
                           y1 * (z1 * sigmoidf_(z1)) * wo1 + xv;
                if (layer == NL - 1) out[base + l] = yv;
                else                 yn[l] = yv;
            }
            __syncthreads();
        }

        // ---- E: halo publish + input swap for next layer ----
        if (layer < NL - 1) {
            if (tid == 0 && c < NC - 1) {
                Hl[c * 4 + 0] = yn[125];
                Hl[c * 4 + 1] = yn[126];
                Hl[c * 4 + 2] = yn[127];
                __hip_atomic_fetch_or(hM, 1u << c, __ATOMIC_RELEASE, __HIP_MEMORY_SCOPE_AGENT);
            }
            xs[3 + tid] = yn[tid];
            if (c > 0) {
                if (tid == 0) {
                    const unsigned bit = 1u << (c - 1);
                    while (!(__hip_atomic_fetch_or(hM, 0u, __ATOMIC_RELAXED,
                                                   __HIP_MEMORY_SCOPE_AGENT) & bit))
                        __builtin_amdgcn_s_sleep(2);
                }
                __syncthreads();
                if (tid < 3) xs[tid] = ucload(&Hl[(c - 1) * 4 + tid]);
            } else {
                if (tid < 3) xs[tid] = 0.0f;
            }
            // top-of-loop __syncthreads orders xs for next preprocess
        }
    }
}

extern "C" void kernel_launch(void* const* d_in, const int* in_sizes, int n_in,
                              void* d_out, int out_size, void* d_ws, size_t ws_size,
                              hipStream_t stream) {
    const float* x      = (const float*)d_in[0];
    const float* W_in   = (const float*)d_in[1];   // [4,1,4]
    const float* conv_w = (const float*)d_in[2];   // [4,2,4]
    const float* conv_b = (const float*)d_in[3];   // [4,2]
    const float* W_x    = (const float*)d_in[4];   // [4,2,129]
    const float* W_dt   = (const float*)d_in[5];   // [4,1,2]
    const float* b_dt   = (const float*)d_in[6];   // [4,2]
    const float* A_log  = (const float*)d_in[7];   // [4,2,64]
    const float* D_skip = (const float*)d_in[8];   // [4,2]
    const float* W_out  = (const float*)d_in[9];   // [4,2,1]
    float* out = (float*)d_out;

    // workspace: masks (256 uints) | Pc | Sc | halo   (~4.3 MB total)
    unsigned* aggMask  = (unsigned*)d_ws;                    // NL*Bsz = 128
    unsigned* haloMask = aggMask + NL * Bsz;                 // 128
    float* Pc   = (float*)d_ws + 256;
    float* Sc   = Pc + (size_t)NL * Bsz * NC * 128;
    float* halo = Sc + (size_t)NL * Bsz * NC * 128;

    hipMemsetAsync(d_ws, 0, 256 * sizeof(unsigned), stream);
    k_mamba_fused<<<dim3(NC, Bsz), 128, 0, stream>>>(
        x, W_in, conv_w, conv_b, W_x, W_dt, b_dt, A_log, D_skip, W_out,
        aggMask, haloMask, Pc, Sc, halo, out);
}

// Round 3
// 221.943 us; speedup vs baseline: 2.4729x; 2.0192x over previous
//
#include <hip/hip_runtime.h>

// MambaSP: back to kernel-boundary ordering (fused spin versions measured 2.5-3x WORSE:
// 417-494us vs 167us -- LLC-latency-exposed spin pipeline at 2 waves/SIMD).
// Structure: per layer, 2 dispatches (8 total):
//   K1: preprocess (conv+silu+softplus) + per-chunk aggregates (P = prod dA, S = local scan)
//   K2: per-block parallel lookback over chunk aggregates (replaces old serial-combine
//       kernel) + re-scan + intra-wave butterfly n-reduction + fused epilogue
// vs round-0 baseline (167us):
//   - K2 combine kernel eliminated (4 fewer dispatches, no 32-step serial LLC chain)
//   - NC 32->64 (CL=64): grid 2048 blocks -> 8 blocks/CU (2x TLP, we are latency-bound)
//   - 33KB ps[] LDS reduction replaced by 6-step __shfl_xor butterfly (LDS ~2KB,
//     occupancy no longer LDS-capped)

constexpr int   Bsz = 32;
constexpr int   Lsz = 4096;
constexpr int   NC  = 64;          // chunks per sequence
constexpr int   CL  = 64;          // chunk length (L/NC)
constexpr float SRinv = 1.0f / 4096.0f;

__device__ __forceinline__ float sigmoidf_(float v) {
    return 1.0f / (1.0f + __expf(-v));
}

// ---------------- K1: preprocess + per-chunk (P,S) ----------------
__global__ __launch_bounds__(128) void k_chunk(
    const float* __restrict__ xin,    // [B,L] layer input
    const float* __restrict__ W_in,   // [4]  (u0,u1,z0,z1 weights)
    const float* __restrict__ conv_w, // [2,4]
    const float* __restrict__ conv_b, // [2]
    const float* __restrict__ W_x,    // [2,129]
    const float* __restrict__ W_dt,   // [2]
    const float* __restrict__ b_dt,   // [2]
    const float* __restrict__ A_log,  // [2,64]
    float4* __restrict__ ud,          // [B*L] {u0,u1,d0,d1}
    float*  __restrict__ Pc,          // [B,NC,128]
    float*  __restrict__ Sc)          // [B,NC,128]
{
    const int c = blockIdx.x, b = blockIdx.y, tid = threadIdx.x;
    __shared__ float  xs[CL + 3];
    __shared__ float4 s_ud[CL];
    const int base = b * Lsz + c * CL;

    // load x with left halo of 3 (zero-padded)
    for (int i = tid; i < CL + 3; i += 128) {
        int l = c * CL + i - 3;
        xs[i] = (l >= 0) ? xin[b * Lsz + l] : 0.0f;
    }
    __syncthreads();

    // preprocess: thread t < CL handles position t
    if (tid < CL) {
        const int t = tid;
        float x0 = xs[t], x1 = xs[t + 1], x2 = xs[t + 2], x3 = xs[t + 3];
        float u[2];
        #pragma unroll
        for (int e = 0; e < 2; e++) {
            float v = W_in[e] * (x0 * conv_w[e * 4 + 0] + x1 * conv_w[e * 4 + 1] +
                                 x2 * conv_w[e * 4 + 2] + x3 * conv_w[e * 4 + 3]) +
                      conv_b[e];
            u[e] = v * sigmoidf_(v);   // silu
        }
        float dt = u[0] * W_x[0] + u[1] * W_x[129];
        float dl[2];
        #pragma unroll
        for (int e = 0; e < 2; e++) {
            float a = dt * W_dt[e] + b_dt[e];
            float sp = (a > 20.0f) ? a : log1pf(__expf(a));
            dl[e] = sp * SRinv;
        }
        float4 v4 = make_float4(u[0], u[1], dl[0], dl[1]);
        s_ud[t] = v4;
        ud[base + t] = v4;
    }
    __syncthreads();

    // chunk scan: thread = (e,n)
    const int e = tid >> 6, n = tid & 63;
    const float Aen = -__expf(A_log[e * 64 + n]);
    const float wb0 = W_x[1 + n], wb1 = W_x[129 + 1 + n];
    float P = 1.0f, S = 0.0f;
    #pragma unroll 8
    for (int l = 0; l < CL; l++) {
        float4 v = s_ud[l];
        float ue = e ? v.y : v.x;
        float d  = e ? v.w : v.z;
        float Bn = v.x * wb0 + v.y * wb1;
        float dA = __expf(d * Aen);
        S = dA * S + (d * ue) * Bn;
        P *= dA;
    }
    const int idx = (b * NC + c) * 128 + tid;
    Pc[idx] = P;
    Sc[idx] = S;
}

// ---------------- K2: lookback + re-scan + butterfly reduction + epilogue ----------------
__global__ __launch_bounds__(128) void k_output(
    const float* __restrict__ xin,
    const float4* __restrict__ ud,
    const float* __restrict__ Pc,
    const float* __restrict__ Sc,
    const float* __restrict__ W_in,   // z weights at [2],[3]
    const float* __restrict__ W_x,
    const float* __restrict__ A_log,
    const float* __restrict__ D_skip, // [2]
    const float* __restrict__ W_out,  // [2]
    float* __restrict__ out)          // [B,L]
{
    const int c = blockIdx.x, b = blockIdx.y, tid = threadIdx.x;
    __shared__ float4 s_ud[CL];
    __shared__ float  ys[2 * CL];
    const int base = b * Lsz + c * CL;

    if (tid < CL) s_ud[tid] = ud[base + tid];

    const int e = tid >> 6, n = tid & 63;
    const float Aen = -__expf(A_log[e * 64 + n]);
    const float wb0 = W_x[1 + n],  wb1 = W_x[129 + 1 + n];
    const float wc0 = W_x[65 + n], wc1 = W_x[129 + 65 + n];
    const float wz0 = W_in[2], wz1 = W_in[3];
    const float D0 = D_skip[0], D1 = D_skip[1];
    const float wo0 = W_out[0], wo1 = W_out[1];

    // per-block parallel lookback: h_in = sum_j (prod_{k>j} P_k) S_j over j<c
    float h = 0.0f;
    if (c > 0) {
        const float* Pb = Pc + (size_t)b * NC * 128 + tid;
        const float* Sb = Sc + (size_t)b * NC * 128 + tid;
        float runS = 0.0f, runP = 1.0f;
        #pragma unroll 8
        for (int j = c - 1; j >= 0; --j) {
            float Sj = Sb[j * 128];
            float Pj = Pb[j * 128];
            runS = __fmaf_rn(runP, Sj, runS);
            runP *= Pj;
        }
        h = runS;
    }
    __syncthreads();   // s_ud ready

    // re-scan with init state; per-step 64-lane butterfly reduce over n
    #pragma unroll 4
    for (int t = 0; t < CL; t++) {
        float4 v = s_ud[t];
        float ue = e ? v.y : v.x;
        float d  = e ? v.w : v.z;
        float Bn = v.x * wb0 + v.y * wb1;
        float Cn = v.x * wc0 + v.y * wc1;
        float dA = __expf(d * Aen);
        h = dA * h + (d * ue) * Bn;
        float p = h * Cn;
        p += __shfl_xor(p, 32, 64);
        p += __shfl_xor(p, 16, 64);
        p += __shfl_xor(p,  8, 64);
        p += __shfl_xor(p,  4, 64);
        p += __shfl_xor(p,  2, 64);
        p += __shfl_xor(p,  1, 64);
        if (n == 0) ys[t * 2 + e] = p + (e ? v.y * D1 : v.x * D0);
    }
    __syncthreads();

    if (tid < CL) {
        float y0 = ys[tid * 2], y1 = ys[tid * 2 + 1];
        float xv = xin[base + tid];
        float z0 = xv * wz0, z1 = xv * wz1;
        out[base + tid] = y0 * (z0 * sigmoidf_(z0)) * wo0 +
                          y1 * (z1 * sigmoidf_(z1)) * wo1 + xv;
    }
}

extern "C" void kernel_launch(void* const* d_in, const int* in_sizes, int n_in,
                              void* d_out, int out_size, void* d_ws, size_t ws_size,
                              hipStream_t stream) {
    const float* x      = (const float*)d_in[0];
    const float* W_in   = (const float*)d_in[1];   // [4,1,4]
    const float* conv_w = (const float*)d_in[2];   // [4,2,4]
    const float* conv_b = (const float*)d_in[3];   // [4,2]
    const float* W_x    = (const float*)d_in[4];   // [4,2,129]
    const float* W_dt   = (const float*)d_in[5];   // [4,1,2]
    const float* b_dt   = (const float*)d_in[6];   // [4,2]
    const float* A_log  = (const float*)d_in[7];   // [4,2,64]
    const float* D_skip = (const float*)d_in[8];   // [4,2]
    const float* W_out  = (const float*)d_in[9];   // [4,2,1]
    float* out = (float*)d_out;

    float* ws   = (float*)d_ws;
    float4* ud  = (float4*)ws;                        // B*L float4
    float* Pc   = ws + (size_t)Bsz * Lsz * 4;         // B*NC*128
    float* Sc   = Pc + (size_t)Bsz * NC * 128;
    float* buf0 = Sc + (size_t)Bsz * NC * 128;
    float* buf1 = buf0 + (size_t)Bsz * Lsz;

    const float* cur = x;
    for (int i = 0; i < 4; i++) {
        float* o = (i == 3) ? out : ((i & 1) ? buf1 : buf0);
        k_chunk<<<dim3(NC, Bsz), 128, 0, stream>>>(
            cur, W_in + i * 4, conv_w + i * 8, conv_b + i * 2,
            W_x + i * 258, W_dt + i * 2, b_dt + i * 2, A_log + i * 128,
            ud, Pc, Sc);
        k_output<<<dim3(NC, Bsz), 128, 0, stream>>>(
            cur, ud, Pc, Sc, W_in + i * 4, W_x + i * 258,
            A_log + i * 128, D_skip + i * 2, W_out + i * 2, o);
        cur = o;
    }
}

// Round 4
// 165.732 us; speedup vs baseline: 3.3116x; 1.3392x over previous
//
#include <hip/hip_runtime.h>
#include <hip/hip_bf16.h>

// MambaSP: 4-layer selective-scan SSM. B=32, L=4096, E=2, N=64, K=4, DT_RANK=1.
// Round-4: exactly the proven round-0 structure (167us; NC=32, CL=128, ps[] reduce)
// with ONE change: the serial combine kernel (K2) is deleted; K3 computes its own
// chunk-entry state via a per-thread parallel lookback over the (P,S) aggregates
// (<=31 independent coalesced loads + 2 FMA each). 8 dispatches instead of 12.
// (Round-3's shfl-butterfly reduce regressed 167->222us: 6 dependent ds_bpermute
//  per step saturated the LDS pipe. Reverted to the throughput-friendly ps[] reduce.)

constexpr int   Bsz = 32;
constexpr int   Lsz = 4096;
constexpr int   NC  = 32;          // chunks per sequence
constexpr int   CL  = 128;         // chunk length (L/NC)
constexpr float SRinv = 1.0f / 4096.0f;

__device__ __forceinline__ float sigmoidf_(float v) {
    return 1.0f / (1.0f + __expf(-v));
}

// ---------------- K1: preprocess + per-chunk (P,S) ----------------
__global__ __launch_bounds__(128) void k_chunk_scan(
    const float* __restrict__ xin,    // [B,L] layer input
    const float* __restrict__ W_in,   // [4]  (u0,u1,z0,z1 weights)
    const float* __restrict__ conv_w, // [2,4]
    const float* __restrict__ conv_b, // [2]
    const float* __restrict__ W_x,    // [2,129]
    const float* __restrict__ W_dt,   // [2]
    const float* __restrict__ b_dt,   // [2]
    const float* __restrict__ A_log,  // [2,64]
    float4* __restrict__ ud,          // [B*L] {u0,u1,d0,d1}
    float*  __restrict__ Pc,          // [B,NC,128]
    float*  __restrict__ Sc)          // [B,NC,128]
{
    const int c = blockIdx.x, b = blockIdx.y, tid = threadIdx.x;
    __shared__ float  xs[CL + 3];
    __shared__ float4 s_ud[CL];
    const int base = b * Lsz + c * CL;

    // load x with left halo of 3 (zero-padded)
    for (int i = tid; i < CL + 3; i += 128) {
        int l = c * CL + i - 3;
        xs[i] = (l >= 0) ? xin[b * Lsz + l] : 0.0f;
    }
    __syncthreads();

    // preprocess: thread t handles position l = t
    {
        const int t = tid;
        float x0 = xs[t], x1 = xs[t + 1], x2 = xs[t + 2], x3 = xs[t + 3];
        float u[2];
        #pragma unroll
        for (int e = 0; e < 2; e++) {
            float v = W_in[e] * (x0 * conv_w[e * 4 + 0] + x1 * conv_w[e * 4 + 1] +
                                 x2 * conv_w[e * 4 + 2] + x3 * conv_w[e * 4 + 3]) +
                      conv_b[e];
            u[e] = v * sigmoidf_(v);   // silu
        }
        float dt = u[0] * W_x[0] + u[1] * W_x[129];
        float dl[2];
        #pragma unroll
        for (int e = 0; e < 2; e++) {
            float a = dt * W_dt[e] + b_dt[e];
            float sp = (a > 20.0f) ? a : log1pf(__expf(a));
            dl[e] = sp * SRinv;
        }
        float4 v4 = make_float4(u[0], u[1], dl[0], dl[1]);
        s_ud[t] = v4;
        ud[base + t] = v4;
    }
    __syncthreads();

    // chunk scan: thread = (e,n)
    const int e = tid >> 6, n = tid & 63;
    const float Aen = -__expf(A_log[e * 64 + n]);
    const float wb0 = W_x[1 + n], wb1 = W_x[129 + 1 + n];
    float P = 1.0f, S = 0.0f;
    #pragma unroll 8
    for (int l = 0; l < CL; l++) {
        float4 v = s_ud[l];
        float ue = e ? v.y : v.x;
        float d  = e ? v.w : v.z;
        float Bn = v.x * wb0 + v.y * wb1;
        float dA = __expf(d * Aen);
        S = dA * S + (d * ue) * Bn;
        P *= dA;
    }
    const int idx = (b * NC + c) * 128 + tid;
    Pc[idx] = P;
    Sc[idx] = S;
}

// ---------------- K3: lookback + re-scan + reduction + epilogue ----------------
__global__ __launch_bounds__(128) void k_output(
    const float* __restrict__ xin,
    const float4* __restrict__ ud,
    const float* __restrict__ Pc,
    const float* __restrict__ Sc,
    const float* __restrict__ W_in,   // z weights at [2],[3]
    const float* __restrict__ W_x,
    const float* __restrict__ A_log,
    const float* __restrict__ D_skip, // [2]
    const float* __restrict__ W_out,  // [2]
    float* __restrict__ out)          // [B,L]
{
    const int c = blockIdx.x, b = blockIdx.y, tid = threadIdx.x;
    constexpr int T = 64;             // steps per reduction tile
    __shared__ float4 s_ud[CL];
    __shared__ float  xs[CL];
    __shared__ float  ps[128 * 65];   // row (t*2+e), stride 65 (bank-safe)
    __shared__ float  ys[T * 2];
    const int base = b * Lsz + c * CL;

    s_ud[tid] = ud[base + tid];
    xs[tid]   = xin[base + tid];

    const int e = tid >> 6, n = tid & 63;
    const float Aen = -__expf(A_log[e * 64 + n]);
    const float wb0 = W_x[1 + n],  wb1 = W_x[129 + 1 + n];
    const float wc0 = W_x[65 + n], wc1 = W_x[129 + 65 + n];
    const float wz0 = W_in[2], wz1 = W_in[3];
    const float D0 = D_skip[0], D1 = D_skip[1];
    const float wo0 = W_out[0], wo1 = W_out[1];

    // parallel lookback: h_in = sum_{j<c} (prod_{j<k<c} P_k) S_j
    float h = 0.0f;
    if (c > 0) {
        const float* Pb = Pc + (size_t)b * NC * 128 + tid;
        const float* Sb = Sc + (size_t)b * NC * 128 + tid;
        float runS = 0.0f, runP = 1.0f;
        #pragma unroll 8
        for (int j = c - 1; j >= 0; --j) {
            float Sj = Sb[j * 128];
            float Pj = Pb[j * 128];
            runS = __fmaf_rn(runP, Sj, runS);
            runP *= Pj;
        }
        h = runS;
    }
    __syncthreads();

    for (int tile = 0; tile < CL / T; tile++) {
        #pragma unroll 8
        for (int t = 0; t < T; t++) {
            float4 v = s_ud[tile * T + t];
            float ue = e ? v.y : v.x;
            float d  = e ? v.w : v.z;
            float Bn = v.x * wb0 + v.y * wb1;
            float Cn = v.x * wc0 + v.y * wc1;
            float dA = __expf(d * Aen);
            h = dA * h + (d * ue) * Bn;
            ps[(t * 2 + e) * 65 + n] = h * Cn;
        }
        __syncthreads();
        // reduce row r=tid over n (64 values), add u*D
        {
            const int r = tid, t = r >> 1, re = r & 1;
            const float* row = &ps[r * 65];
            float a0 = 0, a1 = 0, a2 = 0, a3 = 0;
            #pragma unroll
            for (int j = 0; j < 64; j += 4) {
                a0 += row[j]; a1 += row[j + 1]; a2 += row[j + 2]; a3 += row[j + 3];
            }
            float4 v = s_ud[tile * T + t];
            float ue = re ? v.y : v.x;
            ys[r] = (a0 + a1) + (a2 + a3) + ue * (re ? D1 : D0);
        }
        __syncthreads();
        if (tid < T) {
            int l = tile * T + tid;
            float y0 = ys[tid * 2], y1 = ys[tid * 2 + 1];
            float xv = xs[l];
            float z0 = xv * wz0, z1 = xv * wz1;
            out[base + l] = y0 * (z0 * sigmoidf_(z0)) * wo0 +
                            y1 * (z1 * sigmoidf_(z1)) * wo1 + xv;
        }
        __syncthreads();
    }
}

extern "C" void kernel_launch(void* const* d_in, const int* in_sizes, int n_in,
                              void* d_out, int out_size, void* d_ws, size_t ws_size,
                              hipStream_t stream) {
    const float* x      = (const float*)d_in[0];
    const float* W_in   = (const float*)d_in[1];   // [4,1,4]
    const float* conv_w = (const float*)d_in[2];   // [4,2,4]
    const float* conv_b = (const float*)d_in[3];   // [4,2]
    const float* W_x    = (const float*)d_in[4];   // [4,2,129]
    const float* W_dt   = (const float*)d_in[5];   // [4,1,2]
    const float* b_dt   = (const float*)d_in[6];   // [4,2]
    const float* A_log  = (const float*)d_in[7];   // [4,2,64]
    const float* D_skip = (const float*)d_in[8];   // [4,2]
    const float* W_out  = (const float*)d_in[9];   // [4,2,1]
    float* out = (float*)d_out;

    float* ws   = (float*)d_ws;
    float4* ud  = (float4*)ws;                       // B*L float4s
    float* Pc   = ws + (size_t)Bsz * Lsz * 4;
    float* Sc   = Pc + (size_t)Bsz * NC * 128;
    float* buf0 = Sc + (size_t)Bsz * NC * 128;
    float* buf1 = buf0 + (size_t)Bsz * Lsz;

    const float* cur = x;
    for (int i = 0; i < 4; i++) {
        float* o = (i == 3) ? out : ((i & 1) ? buf1 : buf0);
        k_chunk_scan<<<dim3(NC, Bsz), 128, 0, stream>>>(
            cur, W_in + i * 4, conv_w + i * 8, conv_b + i * 2,
            W_x + i * 258, W_dt + i * 2, b_dt + i * 2, A_log + i * 128,
            ud, Pc, Sc);
        k_output<<<dim3(NC, Bsz), 128, 0, stream>>>(
            cur, ud, Pc, Sc, W_in + i * 4, W_x + i * 258,
            A_log + i * 128, D_skip + i * 2, W_out + i * 2, o);
        cur = o;
    }
}